// Round 2
// baseline (208.229 us; speedup 1.0000x reference)
//
#include <hip/hip_runtime.h>
#include <stdint.h>

typedef short short8 __attribute__((ext_vector_type(8)));
typedef float floatx4 __attribute__((ext_vector_type(4)));

#define NN 100000   // nodes
#define NE 800000   // edges
#define KF 128      // in_feat
#define PC 256      // P cols: [0:128)=P1+b1 (src half), [128:256)=P2 (dst half)
#define LDA 136     // padded LDS row stride (shorts): 2-way bank alias only (free)

// fp32 -> bf16 (RNE)
__device__ __forceinline__ unsigned short f2bf(float x) {
  union { float f; unsigned u; } c; c.f = x;
  unsigned u = c.u + 0x7FFFu + ((c.u >> 16) & 1u);
  return (unsigned short)(u >> 16);
}
// bf16 (low/high half of dword) -> fp32
__device__ __forceinline__ float bfl(unsigned u) {
  union { unsigned u; float f; } c; c.u = u << 16; return c.f;
}
__device__ __forceinline__ float bfh(unsigned u) {
  union { unsigned u; float f; } c; c.u = u & 0xFFFF0000u; return c.f;
}

// ---------------------------------------------------------------------------
// Kernel 1: P[n][j] = sum_k feature[n][k] * Wcat[j][k]  (+ b1[j] for j<128)
//   Wcat[j][k] = (j<128) ? W1[j][k] : W1[j-128][128+k]
// Persistent-W design: each of 4 waves owns 64 output cols; its 16 B-frags
// (64 VGPRs) are loaded ONCE from global (W1 is 128 KB, L2-resident), then a
// grid-stride loop streams 32-node A-tiles through LDS. No W staging per tile.
// ---------------------------------------------------------------------------
extern "C" __global__ void __launch_bounds__(256, 3)
node_proj_kernel(const float* __restrict__ feature,
                 const float* __restrict__ W1,
                 const float* __restrict__ b1,
                 unsigned short* __restrict__ P)
{
  __shared__ unsigned short Al[32 * LDA];  // 8704 B

  const int t    = threadIdx.x;
  const int w    = t >> 6;       // wave 0..3 -> col block w*64
  const int lane = t & 63;
  const int m16  = lane & 15;
  const int quad = lane >> 4;
  const int colBase = w * 64;

  // ---- load persistent B fragments straight from W1 (fp32 -> bf16) ----
  // frag layout (verified in round 1): lane holds W[n][k], n = colBase+ct*16+m16,
  // k = kc*32 + quad*8 + j, j in [0,8)
  short8 bfrag[4][4];
  #pragma unroll
  for (int ct = 0; ct < 4; ++ct) {
    const int n = colBase + ct * 16 + m16;
    const int j = n & 127;            // W1 row
    const int koff = (n >> 7) * 128;  // half offset within W1 row
    #pragma unroll
    for (int kc = 0; kc < 4; ++kc) {
      const float* sp = W1 + j * 256 + koff + kc * 32 + quad * 8;
      float4 f0 = ((const float4*)sp)[0];
      float4 f1 = ((const float4*)sp)[1];
      short8 v;
      v[0] = (short)f2bf(f0.x); v[1] = (short)f2bf(f0.y);
      v[2] = (short)f2bf(f0.z); v[3] = (short)f2bf(f0.w);
      v[4] = (short)f2bf(f1.x); v[5] = (short)f2bf(f1.y);
      v[6] = (short)f2bf(f1.z); v[7] = (short)f2bf(f1.w);
      bfrag[ct][kc] = v;
    }
  }

  float bias[4];
  #pragma unroll
  for (int ct = 0; ct < 4; ++ct)
    bias[ct] = (w < 2) ? b1[colBase + ct * 16 + m16] : 0.f;

  for (int base = blockIdx.x * 32; base < NN; base += gridDim.x * 32) {
    // ---- stage A tile: 32 nodes x 128 k, fp32 -> bf16 ----
    #pragma unroll
    for (int it = 0; it < 2; ++it) {
      int c   = t + it * 256;     // chunk of 8 floats, 0..511
      int nl  = c >> 4;           // local node 0..31
      int kc8 = (c & 15) << 3;    // k offset 0..120
      const float* fp = feature + (size_t)(base + nl) * KF + kc8;
      float4 f0 = ((const float4*)fp)[0];
      float4 f1 = ((const float4*)fp)[1];
      short8 v;
      v[0] = (short)f2bf(f0.x); v[1] = (short)f2bf(f0.y);
      v[2] = (short)f2bf(f0.z); v[3] = (short)f2bf(f0.w);
      v[4] = (short)f2bf(f1.x); v[5] = (short)f2bf(f1.y);
      v[6] = (short)f2bf(f1.z); v[7] = (short)f2bf(f1.w);
      *(short8*)&Al[nl * LDA + kc8] = v;
    }
    __syncthreads();

    short8 afrag[2][4];
    #pragma unroll
    for (int rt = 0; rt < 2; ++rt) {
      const unsigned short* ar = &Al[(rt * 16 + m16) * LDA + quad * 8];
      #pragma unroll
      for (int kc = 0; kc < 4; ++kc)
        afrag[rt][kc] = *(const short8*)(ar + kc * 32);
    }

    floatx4 acc[2][4];
    #pragma unroll
    for (int rt = 0; rt < 2; ++rt)
      #pragma unroll
      for (int ct = 0; ct < 4; ++ct)
        acc[rt][ct] = (floatx4){0.f, 0.f, 0.f, 0.f};

    #pragma unroll
    for (int kc = 0; kc < 4; ++kc)
      #pragma unroll
      for (int rt = 0; rt < 2; ++rt)
        #pragma unroll
        for (int ct = 0; ct < 4; ++ct)
          acc[rt][ct] = __builtin_amdgcn_mfma_f32_16x16x32_bf16(
              afrag[rt][kc], bfrag[ct][kc], acc[rt][ct], 0, 0, 0);

    // ---- epilogue: C layout col=lane&15 (output j), row=quad*4+r (node) ----
    #pragma unroll
    for (int rt = 0; rt < 2; ++rt)
      #pragma unroll
      for (int ct = 0; ct < 4; ++ct) {
        const int col = colBase + ct * 16 + m16;
        #pragma unroll
        for (int r = 0; r < 4; ++r) {
          const int node = base + rt * 16 + quad * 4 + r;
          P[(size_t)node * PC + col] = f2bf(acc[rt][ct][r] + bias[ct]);
        }
      }
    __syncthreads();  // Al reused next iter
  }
}

// ---------------------------------------------------------------------------
// Kernel 2: out[e] = b2 + sum_j relu(P[src[e]][j] + P[dst[e]][128+j]) * W2[j]
// 4 lanes/edge x 2 edges/thread: 16 outstanding dwordx4 gathers per thread
// (latency hiding), 2-step shfl reduction.
// ---------------------------------------------------------------------------
__device__ __forceinline__ float dot8(uint4 u1, uint4 u2, float4 wA, float4 wB) {
  float a = 0.f;
  a += fmaxf(bfl(u1.x) + bfl(u2.x), 0.f) * wA.x;
  a += fmaxf(bfh(u1.x) + bfh(u2.x), 0.f) * wA.y;
  a += fmaxf(bfl(u1.y) + bfl(u2.y), 0.f) * wA.z;
  a += fmaxf(bfh(u1.y) + bfh(u2.y), 0.f) * wA.w;
  a += fmaxf(bfl(u1.z) + bfl(u2.z), 0.f) * wB.x;
  a += fmaxf(bfh(u1.z) + bfh(u2.z), 0.f) * wB.y;
  a += fmaxf(bfl(u1.w) + bfl(u2.w), 0.f) * wB.z;
  a += fmaxf(bfh(u1.w) + bfh(u2.w), 0.f) * wB.w;
  return a;
}

extern "C" __global__ void __launch_bounds__(256)
edge_score_kernel(const unsigned short* __restrict__ P,
                  const int* __restrict__ src,
                  const int* __restrict__ dst,
                  const float* __restrict__ W2,
                  const float* __restrict__ b2,
                  float* __restrict__ out)
{
  const int t  = threadIdx.x;
  const int l4 = t & 3;                       // lane within edge group
  const int g  = t >> 2;                      // edge group 0..63
  const int e0 = blockIdx.x * 128 + g;        // 128 edges per block
  const int e1 = e0 + 64;

  const int s0 = src[e0], d0 = dst[e0];
  const int s1 = src[e1], d1 = dst[e1];

  // each lane covers 32 consecutive j (64 B) of each half
  const uint4* p1a = (const uint4*)(P + (size_t)s0 * PC + l4 * 32);
  const uint4* p2a = (const uint4*)(P + (size_t)d0 * PC + 128 + l4 * 32);
  const uint4* p1b = (const uint4*)(P + (size_t)s1 * PC + l4 * 32);
  const uint4* p2b = (const uint4*)(P + (size_t)d1 * PC + 128 + l4 * 32);

  uint4 a0 = p1a[0], a1 = p1a[1], a2 = p1a[2], a3 = p1a[3];
  uint4 b0 = p2a[0], b1v = p2a[1], b2v = p2a[2], b3 = p2a[3];
  uint4 c0 = p1b[0], c1 = p1b[1], c2 = p1b[2], c3 = p1b[3];
  uint4 e0v = p2b[0], e1v = p2b[1], e2v = p2b[2], e3 = p2b[3];

  const float4* wp = (const float4*)(W2 + l4 * 32);
  float4 w0 = wp[0], w1 = wp[1], w2 = wp[2], w3 = wp[3];
  float4 w4 = wp[4], w5 = wp[5], w6 = wp[6], w7 = wp[7];

  float accA = dot8(a0, b0, w0, w1) + dot8(a1, b1v, w2, w3)
             + dot8(a2, b2v, w4, w5) + dot8(a3, b3, w6, w7);
  float accB = dot8(c0, e0v, w0, w1) + dot8(c1, e1v, w2, w3)
             + dot8(c2, e2v, w4, w5) + dot8(c3, e3, w6, w7);

  accA += __shfl_xor(accA, 2);
  accA += __shfl_xor(accA, 1);
  accB += __shfl_xor(accB, 2);
  accB += __shfl_xor(accB, 1);

  if (l4 == 0) {
    const float bb = b2[0];
    out[e0] = accA + bb;
    out[e1] = accB + bb;
  }
}

extern "C" void kernel_launch(void* const* d_in, const int* in_sizes, int n_in,
                              void* d_out, int out_size, void* d_ws, size_t ws_size,
                              hipStream_t stream)
{
  const float* feature = (const float*)d_in[0];
  const int*   src     = (const int*)d_in[1];
  const int*   dst     = (const int*)d_in[2];
  const float* W1      = (const float*)d_in[3];
  const float* b1      = (const float*)d_in[4];
  const float* W2      = (const float*)d_in[5];
  const float* b2      = (const float*)d_in[6];
  float* out = (float*)d_out;
  unsigned short* P = (unsigned short*)d_ws;  // [NN][256] bf16, 51.2 MB

  node_proj_kernel<<<768, 256, 0, stream>>>(feature, W1, b1, P);      // 3 blocks/CU
  edge_score_kernel<<<NE / 128, 256, 0, stream>>>(P, src, dst, W2, b2, out);  // 6250 blocks
}

// Round 3
// 184.271 us; speedup vs baseline: 1.1300x; 1.1300x over previous
//
#include <hip/hip_runtime.h>
#include <stdint.h>

typedef short short8 __attribute__((ext_vector_type(8)));
typedef float floatx4 __attribute__((ext_vector_type(4)));

#define NN 100000   // nodes
#define NE 800000   // edges
#define KF 128      // in_feat
#define PC 256      // P cols: [0:128)=P1+b1 (src half), [128:256)=P2 (dst half)
#define LDA 136     // Al row stride (shorts)
#define LDO 274     // Po row stride (shorts)

// fp32 -> bf16 (RNE)
__device__ __forceinline__ unsigned short f2bf(float x) {
  union { float f; unsigned u; } c; c.f = x;
  unsigned u = c.u + 0x7FFFu + ((c.u >> 16) & 1u);
  return (unsigned short)(u >> 16);
}
__device__ __forceinline__ float bfl(unsigned u) {
  union { unsigned u; float f; } c; c.u = u << 16; return c.f;
}
__device__ __forceinline__ float bfh(unsigned u) {
  union { unsigned u; float f; } c; c.u = u & 0xFFFF0000u; return c.f;
}

// ---------------------------------------------------------------------------
// Kernel 1: P[n][j] = sum_k feature[n][k] * Wcat[j][k]  (+ b1[j] for j<128)
// 1563 independent blocks, tile = 64 nodes x 256 cols. Persistent B-frags in
// VGPRs (loaded once per block from L2-resident W1). One barrier for A-stage,
// then per-16-node-group: 16 MFMAs -> LDS transpose -> coalesced 16B stores.
// ---------------------------------------------------------------------------
extern "C" __global__ void __launch_bounds__(256)
node_proj_kernel(const float* __restrict__ feature,
                 const float* __restrict__ W1,
                 const float* __restrict__ b1,
                 unsigned short* __restrict__ P)
{
  __shared__ unsigned short Al[64 * LDA];  // 17408 B
  __shared__ unsigned short Po[16 * LDO];  //  8768 B

  const int t    = threadIdx.x;
  const int w    = t >> 6;       // wave 0..3 -> col block w*64
  const int lane = t & 63;
  const int m16  = lane & 15;
  const int quad = lane >> 4;
  const int colBase  = w * 64;
  const int tileBase = blockIdx.x * 64;

  // ---- persistent B fragments (fp32 -> bf16), 64 VGPRs/thread ----
  // lane holds Wcat[n][k]: n = colBase+ct*16+m16, k = kc*32+quad*8+j
  short8 bfrag[4][4];
  #pragma unroll
  for (int ct = 0; ct < 4; ++ct) {
    const int n = colBase + ct * 16 + m16;
    const int j = n & 127;            // W1 row
    const int koff = (n >> 7) * 128;  // which 128-half of the W1 row
    #pragma unroll
    for (int kc = 0; kc < 4; ++kc) {
      const float* sp = W1 + j * 256 + koff + kc * 32 + quad * 8;
      float4 f0 = ((const float4*)sp)[0];
      float4 f1 = ((const float4*)sp)[1];
      short8 v;
      v[0] = (short)f2bf(f0.x); v[1] = (short)f2bf(f0.y);
      v[2] = (short)f2bf(f0.z); v[3] = (short)f2bf(f0.w);
      v[4] = (short)f2bf(f1.x); v[5] = (short)f2bf(f1.y);
      v[6] = (short)f2bf(f1.z); v[7] = (short)f2bf(f1.w);
      bfrag[ct][kc] = v;
    }
  }

  float bias[4];
  #pragma unroll
  for (int ct = 0; ct < 4; ++ct)
    bias[ct] = (w < 2) ? b1[colBase + ct * 16 + m16] : 0.f;

  // ---- stage A tile: 64 nodes x 128 k (fp32 -> bf16) ----
  #pragma unroll
  for (int it = 0; it < 4; ++it) {
    int c   = t + it * 256;     // chunk of 8 floats, 0..1023
    int nl  = c >> 4;           // local node 0..63
    int kc8 = (c & 15) << 3;    // k offset 0..120
    int node = tileBase + nl;
    float4 f0 = make_float4(0.f, 0.f, 0.f, 0.f);
    float4 f1 = make_float4(0.f, 0.f, 0.f, 0.f);
    if (node < NN) {
      const float* fp = feature + (size_t)node * KF + kc8;
      f0 = ((const float4*)fp)[0];
      f1 = ((const float4*)fp)[1];
    }
    short8 v;
    v[0] = (short)f2bf(f0.x); v[1] = (short)f2bf(f0.y);
    v[2] = (short)f2bf(f0.z); v[3] = (short)f2bf(f0.w);
    v[4] = (short)f2bf(f1.x); v[5] = (short)f2bf(f1.y);
    v[6] = (short)f2bf(f1.z); v[7] = (short)f2bf(f1.w);
    *(short8*)&Al[nl * LDA + kc8] = v;
  }
  __syncthreads();

  #pragma unroll
  for (int rt = 0; rt < 4; ++rt) {       // 16-node group
    short8 afrag[4];
    const unsigned short* ar = &Al[(rt * 16 + m16) * LDA + quad * 8];
    #pragma unroll
    for (int kc = 0; kc < 4; ++kc)
      afrag[kc] = *(const short8*)(ar + kc * 32);

    floatx4 acc[4];
    #pragma unroll
    for (int ct = 0; ct < 4; ++ct) acc[ct] = (floatx4){0.f, 0.f, 0.f, 0.f};

    #pragma unroll
    for (int kc = 0; kc < 4; ++kc)
      #pragma unroll
      for (int ct = 0; ct < 4; ++ct)
        acc[ct] = __builtin_amdgcn_mfma_f32_16x16x32_bf16(
            afrag[kc], bfrag[ct][kc], acc[ct], 0, 0, 0);

    // C layout: col = ct*16+m16, local row = quad*4+r
    #pragma unroll
    for (int ct = 0; ct < 4; ++ct)
      #pragma unroll
      for (int r = 0; r < 4; ++r)
        Po[(quad * 4 + r) * LDO + colBase + ct * 16 + m16] =
            f2bf(acc[ct][r] + bias[ct]);
    __syncthreads();

    // coalesced store: thread t writes 32 B of row (t>>4)
    {
      const int row  = t >> 4;            // 0..15
      const int seg  = (t & 15) * 16;     // short offset 0..240
      const int node = tileBase + rt * 16 + row;
      if (node < NN) {
        const uint4* sp = (const uint4*)&Po[row * LDO + seg];
        uint4* dp = (uint4*)(P + (size_t)node * PC + seg);
        dp[0] = sp[0];
        dp[1] = sp[1];
      }
    }
    __syncthreads();   // Po reused next rt
  }
}

// ---------------------------------------------------------------------------
// Kernel 2: out[e] = b2 + sum_j relu(P[src[e]][j] + P[dst[e]][128+j]) * W2[j]
// 16 lanes/edge (contiguous 256 B per edge-half per instruction), 4 edges per
// thread -> 8 outstanding dwordx4 gathers. lane0 stores a coalesced float4.
// ---------------------------------------------------------------------------
__device__ __forceinline__ float dot8(uint4 u1, uint4 u2, float4 wA, float4 wB) {
  float a = 0.f;
  a += fmaxf(bfl(u1.x) + bfl(u2.x), 0.f) * wA.x;
  a += fmaxf(bfh(u1.x) + bfh(u2.x), 0.f) * wA.y;
  a += fmaxf(bfl(u1.y) + bfl(u2.y), 0.f) * wA.z;
  a += fmaxf(bfh(u1.y) + bfh(u2.y), 0.f) * wA.w;
  a += fmaxf(bfl(u1.z) + bfl(u2.z), 0.f) * wB.x;
  a += fmaxf(bfh(u1.z) + bfh(u2.z), 0.f) * wB.y;
  a += fmaxf(bfl(u1.w) + bfl(u2.w), 0.f) * wB.z;
  a += fmaxf(bfh(u1.w) + bfh(u2.w), 0.f) * wB.w;
  return a;
}

extern "C" __global__ void __launch_bounds__(256)
edge_score_kernel(const unsigned short* __restrict__ P,
                  const int* __restrict__ src,
                  const int* __restrict__ dst,
                  const float* __restrict__ W2,
                  const float* __restrict__ b2,
                  float* __restrict__ out)
{
  const int t    = threadIdx.x;
  const int lane = t & 15;
  const int g    = t >> 4;                 // group 0..15
  const int e0   = blockIdx.x * 64 + g * 4;  // 4 consecutive edges per group

  const int s0 = src[e0],     d0 = dst[e0];
  const int s1 = src[e0 + 1], d1 = dst[e0 + 1];
  const int s2 = src[e0 + 2], d2 = dst[e0 + 2];
  const int s3 = src[e0 + 3], d3 = dst[e0 + 3];

  const size_t lo = (size_t)(lane * 8);
  const uint4 a0 = *(const uint4*)(P + (size_t)s0 * PC + lo);
  const uint4 b0 = *(const uint4*)(P + (size_t)d0 * PC + 128 + lo);
  const uint4 a1 = *(const uint4*)(P + (size_t)s1 * PC + lo);
  const uint4 b1v = *(const uint4*)(P + (size_t)d1 * PC + 128 + lo);
  const uint4 a2 = *(const uint4*)(P + (size_t)s2 * PC + lo);
  const uint4 b2v = *(const uint4*)(P + (size_t)d2 * PC + 128 + lo);
  const uint4 a3 = *(const uint4*)(P + (size_t)s3 * PC + lo);
  const uint4 b3v = *(const uint4*)(P + (size_t)d3 * PC + 128 + lo);

  const float4 wA = *(const float4*)(W2 + lane * 8);
  const float4 wB = *(const float4*)(W2 + lane * 8 + 4);

  float r0 = dot8(a0, b0, wA, wB);
  float r1 = dot8(a1, b1v, wA, wB);
  float r2 = dot8(a2, b2v, wA, wB);
  float r3 = dot8(a3, b3v, wA, wB);

  #pragma unroll
  for (int s = 8; s >= 1; s >>= 1) {
    r0 += __shfl_xor(r0, s);
    r1 += __shfl_xor(r1, s);
    r2 += __shfl_xor(r2, s);
    r3 += __shfl_xor(r3, s);
  }

  if (lane == 0) {
    const float bb = b2[0];
    *(float4*)(out + e0) = make_float4(r0 + bb, r1 + bb, r2 + bb, r3 + bb);
  }
}

extern "C" void kernel_launch(void* const* d_in, const int* in_sizes, int n_in,
                              void* d_out, int out_size, void* d_ws, size_t ws_size,
                              hipStream_t stream)
{
  const float* feature = (const float*)d_in[0];
  const int*   src     = (const int*)d_in[1];
  const int*   dst     = (const int*)d_in[2];
  const float* W1      = (const float*)d_in[3];
  const float* b1      = (const float*)d_in[4];
  const float* W2      = (const float*)d_in[5];
  const float* b2      = (const float*)d_in[6];
  float* out = (float*)d_out;
  unsigned short* P = (unsigned short*)d_ws;  // [NN][256] bf16, 51.2 MB

  node_proj_kernel<<<(NN + 63) / 64, 256, 0, stream>>>(feature, W1, b1, P);  // 1563 blocks
  edge_score_kernel<<<NE / 64, 256, 0, stream>>>(P, src, dst, W2, b2, out);  // 12500 blocks
}

// Round 4
// 179.687 us; speedup vs baseline: 1.1588x; 1.0255x over previous
//
#include <hip/hip_runtime.h>
#include <stdint.h>

typedef short short8 __attribute__((ext_vector_type(8)));
typedef float floatx4 __attribute__((ext_vector_type(4)));

#define NN 100000   // nodes
#define NE 800000   // edges
#define KF 128      // in_feat
#define PC 256      // P cols: [0:128)=P1+b1 (src half), [128:256)=P2 (dst half)
#define LDA 136     // Al row stride (shorts): 68 dwords -> 2-way alias only (free)
#define LDO 274     // Po row stride (shorts): 137 dwords (odd) -> staggered banks

// fp32 -> bf16 (RNE)
__device__ __forceinline__ unsigned short f2bf(float x) {
  union { float f; unsigned u; } c; c.f = x;
  unsigned u = c.u + 0x7FFFu + ((c.u >> 16) & 1u);
  return (unsigned short)(u >> 16);
}
__device__ __forceinline__ float bfl(unsigned u) {
  union { unsigned u; float f; } c; c.u = u << 16; return c.f;
}
__device__ __forceinline__ float bfh(unsigned u) {
  union { unsigned u; float f; } c; c.u = u & 0xFFFF0000u; return c.f;
}

// ---------------------------------------------------------------------------
// Kernel 1: P[n][j] = sum_k feature[n][k] * Wcat[j][k]  (+ b1[j] for j<128)
//   Wcat[j][k] = (j<128) ? W1[j][k] : W1[j-128][128+k]
// 1563 blocks, tile = 64 nodes x 256 cols. Persistent B-frags in VGPRs
// (loaded once per block; W1 is 128 KB, L2-resident). Exactly TWO barriers
// per block: A-stage -> MFMA+Po writes (no barriers between 16-node groups,
// each writes disjoint Po rows) -> bulk coalesced dwordx4 store.
// ---------------------------------------------------------------------------
extern "C" __global__ void __launch_bounds__(256)
node_proj_kernel(const float* __restrict__ feature,
                 const float* __restrict__ W1,
                 const float* __restrict__ b1,
                 unsigned short* __restrict__ P)
{
  __shared__ unsigned short Al[64 * LDA];  // 17408 B
  __shared__ unsigned short Po[64 * LDO];  // 35072 B  (52.5 KB total -> 3 blk/CU)

  const int t    = threadIdx.x;
  const int w    = t >> 6;       // wave 0..3 -> col block w*64
  const int lane = t & 63;
  const int m16  = lane & 15;
  const int quad = lane >> 4;
  const int colBase  = w * 64;
  const int tileBase = blockIdx.x * 64;

  // ---- persistent B fragments (fp32 -> bf16), 64 VGPRs/thread ----
  // lane holds Wcat[n][k]: n = colBase+ct*16+m16, k = kc*32+quad*8+j
  short8 bfrag[4][4];
  #pragma unroll
  for (int ct = 0; ct < 4; ++ct) {
    const int n = colBase + ct * 16 + m16;
    const int j = n & 127;            // W1 row
    const int koff = (n >> 7) * 128;  // which 128-half of the W1 row
    #pragma unroll
    for (int kc = 0; kc < 4; ++kc) {
      const float* sp = W1 + j * 256 + koff + kc * 32 + quad * 8;
      float4 f0 = ((const float4*)sp)[0];
      float4 f1 = ((const float4*)sp)[1];
      short8 v;
      v[0] = (short)f2bf(f0.x); v[1] = (short)f2bf(f0.y);
      v[2] = (short)f2bf(f0.z); v[3] = (short)f2bf(f0.w);
      v[4] = (short)f2bf(f1.x); v[5] = (short)f2bf(f1.y);
      v[6] = (short)f2bf(f1.z); v[7] = (short)f2bf(f1.w);
      bfrag[ct][kc] = v;
    }
  }

  float bias[4];
  #pragma unroll
  for (int ct = 0; ct < 4; ++ct)
    bias[ct] = (w < 2) ? b1[colBase + ct * 16 + m16] : 0.f;

  // ---- stage A tile: 64 nodes x 128 k (fp32 -> bf16) ----
  #pragma unroll
  for (int it = 0; it < 4; ++it) {
    int c   = t + it * 256;     // chunk of 8 floats, 0..1023
    int nl  = c >> 4;           // local node 0..63
    int kc8 = (c & 15) << 3;    // k offset 0..120
    int node = tileBase + nl;
    float4 f0 = make_float4(0.f, 0.f, 0.f, 0.f);
    float4 f1 = make_float4(0.f, 0.f, 0.f, 0.f);
    if (node < NN) {
      const float* fp = feature + (size_t)node * KF + kc8;
      f0 = ((const float4*)fp)[0];
      f1 = ((const float4*)fp)[1];
    }
    short8 v;
    v[0] = (short)f2bf(f0.x); v[1] = (short)f2bf(f0.y);
    v[2] = (short)f2bf(f0.z); v[3] = (short)f2bf(f0.w);
    v[4] = (short)f2bf(f1.x); v[5] = (short)f2bf(f1.y);
    v[6] = (short)f2bf(f1.z); v[7] = (short)f2bf(f1.w);
    *(short8*)&Al[nl * LDA + kc8] = v;
  }
  __syncthreads();   // barrier 1

  #pragma unroll
  for (int rt = 0; rt < 4; ++rt) {       // 16-node group; writes disjoint Po rows
    short8 afrag[4];
    const unsigned short* ar = &Al[(rt * 16 + m16) * LDA + quad * 8];
    #pragma unroll
    for (int kc = 0; kc < 4; ++kc)
      afrag[kc] = *(const short8*)(ar + kc * 32);

    floatx4 acc[4];
    #pragma unroll
    for (int ct = 0; ct < 4; ++ct) acc[ct] = (floatx4){0.f, 0.f, 0.f, 0.f};

    #pragma unroll
    for (int kc = 0; kc < 4; ++kc)
      #pragma unroll
      for (int ct = 0; ct < 4; ++ct)
        acc[ct] = __builtin_amdgcn_mfma_f32_16x16x32_bf16(
            afrag[kc], bfrag[ct][kc], acc[ct], 0, 0, 0);

    // C layout: col = ct*16+m16, local row = rt*16 + quad*4 + r
    #pragma unroll
    for (int ct = 0; ct < 4; ++ct)
      #pragma unroll
      for (int r = 0; r < 4; ++r)
        Po[(rt * 16 + quad * 4 + r) * LDO + colBase + ct * 16 + m16] =
            f2bf(acc[ct][r] + bias[ct]);
  }
  __syncthreads();   // barrier 2

  // ---- bulk coalesced store: 32 lanes cover one 512 B row ----
  #pragma unroll
  for (int i = 0; i < 8; ++i) {
    const int flat = t + i * 256;        // 16 B chunk id, 0..2047
    const int row  = flat >> 5;          // local node 0..63
    const int cic  = flat & 31;          // chunk in row
    const int node = tileBase + row;
    if (node < NN) {
      *(uint4*)(P + (size_t)node * PC + cic * 8) =
          *(const uint4*)&Po[row * LDO + cic * 8];
    }
  }
}

// ---------------------------------------------------------------------------
// Kernel 2: out[e] = b2 + sum_j relu(P[src[e]][j] + P[dst[e]][128+j]) * W2[j]
// 16 lanes/edge (contiguous 256 B per edge-half per instruction), 4 edges per
// thread -> 8 outstanding dwordx4 gathers. lane0 stores a coalesced float4.
// ---------------------------------------------------------------------------
__device__ __forceinline__ float dot8(uint4 u1, uint4 u2, float4 wA, float4 wB) {
  float a = 0.f;
  a += fmaxf(bfl(u1.x) + bfl(u2.x), 0.f) * wA.x;
  a += fmaxf(bfh(u1.x) + bfh(u2.x), 0.f) * wA.y;
  a += fmaxf(bfl(u1.y) + bfl(u2.y), 0.f) * wA.z;
  a += fmaxf(bfh(u1.y) + bfh(u2.y), 0.f) * wA.w;
  a += fmaxf(bfl(u1.z) + bfl(u2.z), 0.f) * wB.x;
  a += fmaxf(bfh(u1.z) + bfh(u2.z), 0.f) * wB.y;
  a += fmaxf(bfl(u1.w) + bfl(u2.w), 0.f) * wB.z;
  a += fmaxf(bfh(u1.w) + bfh(u2.w), 0.f) * wB.w;
  return a;
}

extern "C" __global__ void __launch_bounds__(256)
edge_score_kernel(const unsigned short* __restrict__ P,
                  const int* __restrict__ src,
                  const int* __restrict__ dst,
                  const float* __restrict__ W2,
                  const float* __restrict__ b2,
                  float* __restrict__ out)
{
  const int t    = threadIdx.x;
  const int lane = t & 15;
  const int g    = t >> 4;                 // group 0..15
  const int e0   = blockIdx.x * 64 + g * 4;  // 4 consecutive edges per group

  const int s0 = src[e0],     d0 = dst[e0];
  const int s1 = src[e0 + 1], d1 = dst[e0 + 1];
  const int s2 = src[e0 + 2], d2 = dst[e0 + 2];
  const int s3 = src[e0 + 3], d3 = dst[e0 + 3];

  const size_t lo = (size_t)(lane * 8);
  const uint4 a0 = *(const uint4*)(P + (size_t)s0 * PC + lo);
  const uint4 b0 = *(const uint4*)(P + (size_t)d0 * PC + 128 + lo);
  const uint4 a1 = *(const uint4*)(P + (size_t)s1 * PC + lo);
  const uint4 b1v = *(const uint4*)(P + (size_t)d1 * PC + 128 + lo);
  const uint4 a2 = *(const uint4*)(P + (size_t)s2 * PC + lo);
  const uint4 b2v = *(const uint4*)(P + (size_t)d2 * PC + 128 + lo);
  const uint4 a3 = *(const uint4*)(P + (size_t)s3 * PC + lo);
  const uint4 b3v = *(const uint4*)(P + (size_t)d3 * PC + 128 + lo);

  const float4 wA = *(const float4*)(W2 + lane * 8);
  const float4 wB = *(const float4*)(W2 + lane * 8 + 4);

  float r0 = dot8(a0, b0, wA, wB);
  float r1 = dot8(a1, b1v, wA, wB);
  float r2 = dot8(a2, b2v, wA, wB);
  float r3 = dot8(a3, b3v, wA, wB);

  #pragma unroll
  for (int s = 8; s >= 1; s >>= 1) {
    r0 += __shfl_xor(r0, s);
    r1 += __shfl_xor(r1, s);
    r2 += __shfl_xor(r2, s);
    r3 += __shfl_xor(r3, s);
  }

  if (lane == 0) {
    const float bb = b2[0];
    *(float4*)(out + e0) = make_float4(r0 + bb, r1 + bb, r2 + bb, r3 + bb);
  }
}

extern "C" void kernel_launch(void* const* d_in, const int* in_sizes, int n_in,
                              void* d_out, int out_size, void* d_ws, size_t ws_size,
                              hipStream_t stream)
{
  const float* feature = (const float*)d_in[0];
  const int*   src     = (const int*)d_in[1];
  const int*   dst     = (const int*)d_in[2];
  const float* W1      = (const float*)d_in[3];
  const float* b1      = (const float*)d_in[4];
  const float* W2      = (const float*)d_in[5];
  const float* b2      = (const float*)d_in[6];
  float* out = (float*)d_out;
  unsigned short* P = (unsigned short*)d_ws;  // [NN][256] bf16, 51.2 MB

  node_proj_kernel<<<(NN + 63) / 64, 256, 0, stream>>>(feature, W1, b1, P);  // 1563 blocks
  edge_score_kernel<<<NE / 64, 256, 0, stream>>>(P, src, dst, W2, b2, out);  // 12500 blocks
}